// Round 1
// baseline (1424.635 us; speedup 1.0000x reference)
//
#include <hip/hip_runtime.h>
#include <cstdint>
#include <cmath>

using u16 = unsigned short;
using u8  = unsigned char;
using u32 = unsigned int;

typedef __attribute__((ext_vector_type(8))) short short8;
typedef __attribute__((ext_vector_type(8))) unsigned short u16x8;
typedef __attribute__((ext_vector_type(4))) float f32x4;

#define DEV static __device__ __forceinline__

DEV u16 f2bf(float f) {               // fp32 -> bf16 RNE
  u32 u = __builtin_bit_cast(u32, f);
  u = u + 0x7fffu + ((u >> 16) & 1u);
  return (u16)(u >> 16);
}
DEV float bf2f(u16 h) { return __builtin_bit_cast(float, ((u32)h) << 16); }

// ---------------- weight staging: linear 16B copy (packed layout is already fragment order)
DEV void stageW(const u16* __restrict__ src, u16* dst, int nush, int tid, int nthr) {
  const uint4* s = (const uint4*)src;
  uint4* d = (uint4*)dst;
  int n16 = nush >> 3;
  for (int i = tid; i < n16; i += nthr) d[i] = s[i];
}

// ---------------- MFMA over one staged 64-K chunk. A: LDS row-major bf16 (stride u16s).
// B (wt): swizzled [(kb*4+quad)*ncols + n]*8 + j  so each lane reads 16B contiguous.
// 16x16x32 layouts: A[m=lane&15][k=quad*8+j], B[k=quad*8+j][n=lane&15], C row=quad*4+reg,col=lane&15.
template<int NT>
DEV void mfma_chunk(const u16* act, int strideA, int kbase,
                    const u16* wt, int ncols, int rt, int cbase,
                    f32x4* acc, int lane) {
  int l15 = lane & 15, quad = lane >> 4;
  const u16* arow = act + (rt*16 + l15) * strideA + kbase + quad*8;
#pragma unroll
  for (int kb = 0; kb < 2; ++kb) {
    short8 af = *(const short8*)(arow + kb*32);
    const u16* wrow = wt + ((kb*4 + quad) * ncols + l15) * 8;
#pragma unroll
    for (int t = 0; t < NT; ++t) {
      short8 bf = *(const short8*)(wrow + (cbase + t) * 16 * 8);
      acc[t] = __builtin_amdgcn_mfma_f32_16x16x32_bf16(af, bf, acc[t], 0, 0, 0);
    }
  }
}

// K=128 GEMM phase: stage 2x 64-K chunks (wt LDS holds 64 x ncols bf16)
template<int NT>
DEV void run_gemm128(const u16* wsrc, const u16* act, int strideA, int kbase,
                     int ncols, f32x4* acc, u16* wt, int tid, int nthr,
                     int rt, int cbase, int lane) {
  int nush = 64 * ncols;
  stageW(wsrc, wt, nush, tid, nthr);
  __syncthreads();
  mfma_chunk<NT>(act, strideA, kbase, wt, ncols, rt, cbase, acc, lane);
  __syncthreads();
  stageW(wsrc + nush, wt, nush, tid, nthr);
  __syncthreads();
  mfma_chunk<NT>(act, strideA, kbase + 64, wt, ncols, rt, cbase, acc, lane);
  __syncthreads();
}

// ---------------- epilogues ----------------
// LayerNorm epilogue: v = acc + bias + resid(xf); row-mean/var via 16-lane butterfly +
// 2-half LDS combine; writes post-LN to xf (fp32 resid for next LN) and act (bf16 A-input).
DEV void ln_epilogue(f32x4* acc, int rt, int cbase, int wave, int lane,
                     const float* __restrict__ bias, const float* __restrict__ g,
                     const float* __restrict__ be,
                     float* xf, u16* act, float* red) {
  int l15 = lane & 15, quad = lane >> 4;
  int half = wave & 1;
  float v[4][4];
  float s[4] = {0.f,0.f,0.f,0.f}, ss[4] = {0.f,0.f,0.f,0.f};
#pragma unroll
  for (int t = 0; t < 4; ++t) {
    int col = (cbase + t)*16 + l15;
    float b = bias[col];
#pragma unroll
    for (int r = 0; r < 4; ++r) {
      int row = rt*16 + quad*4 + r;
      float val = acc[t][r] + b + xf[row*132 + col];
      v[t][r] = val;
      s[r] += val; ss[r] += val*val;
    }
  }
#pragma unroll
  for (int m = 1; m < 16; m <<= 1) {
#pragma unroll
    for (int r = 0; r < 4; ++r) {
      s[r]  += __shfl_xor(s[r],  m);
      ss[r] += __shfl_xor(ss[r], m);
    }
  }
  if (l15 == 0) {
#pragma unroll
    for (int r = 0; r < 4; ++r) {
      int row = rt*16 + quad*4 + r;
      red[row*4 + half*2 + 0] = s[r];
      red[row*4 + half*2 + 1] = ss[r];
    }
  }
  __syncthreads();
#pragma unroll
  for (int r = 0; r < 4; ++r) {
    int row = rt*16 + quad*4 + r;
    float st  = red[row*4 + 0] + red[row*4 + 2];
    float sst = red[row*4 + 1] + red[row*4 + 3];
    float mean = st * (1.f/128.f);
    float var  = sst * (1.f/128.f) - mean*mean;
    float rs = rsqrtf(var + 1e-5f);
#pragma unroll
    for (int t = 0; t < 4; ++t) {
      int col = (cbase + t)*16 + l15;
      float xn = (v[t][r] - mean) * rs * g[col] + be[col];
      xf[row*132 + col]  = xn;
      act[row*136 + col] = f2bf(xn);
    }
  }
  __syncthreads();
}

DEV void relu_epilogue(f32x4* acc, int rt, int cbase, int lane,
                       const float* __restrict__ bias, int colbase, u16* h1) {
  int l15 = lane & 15, quad = lane >> 4;
#pragma unroll
  for (int t = 0; t < 4; ++t) {
    int col = (cbase + t)*16 + l15;
    float b = bias[colbase + col];
#pragma unroll
    for (int r = 0; r < 4; ++r) {
      int row = rt*16 + quad*4 + r;
      float val = fmaxf(acc[t][r] + b, 0.f);
      h1[row*264 + colbase + col] = f2bf(val);
    }
  }
}

DEV void q_epilogue(f32x4* acc, int rt, int cbase, int lane, u16* dst) {
  int l15 = lane & 15, quad = lane >> 4;
#pragma unroll
  for (int t = 0; t < 4; ++t)
#pragma unroll
    for (int r = 0; r < 4; ++r)
      dst[(rt*16 + quad*4 + r)*264 + (cbase + t)*16 + l15] = f2bf(acc[t][r]);
}

// ---------------- attention: thread = (node, head); softmax fully thread-local over K=5
DEV void attention(const u16* __restrict__ Pg, const int* s_nidx, const u8* s_nval,
                   const u16* qbuf, u16* act, int layerOff, int tid) {
  int nl = tid >> 3, h = tid & 7;
  float q[16];
  {
    const u16* qp = qbuf + nl*264 + h*16;
    u16x8 q0 = *(const u16x8*)qp;
    u16x8 q1 = *(const u16x8*)(qp + 8);
#pragma unroll
    for (int i = 0; i < 8; ++i) { q[i] = bf2f(q0[i]); q[8+i] = bf2f(q1[i]); }
  }
  float sc[5], w[5];
  int mlist[5], vmask[5];
  float mx = -1e30f;
#pragma unroll
  for (int j = 0; j < 5; ++j) {
    int mj = s_nidx[nl*5 + j];
    int vj = s_nval[nl*5 + j];
    mlist[j] = mj; vmask[j] = vj;
    const u16* kr = Pg + (size_t)mj*512 + layerOff + h*16;
    u16x8 k0 = *(const u16x8*)kr;
    u16x8 k1 = *(const u16x8*)(kr + 8);
    float d = 0.f;
#pragma unroll
    for (int i = 0; i < 8; ++i) d += bf2f(k0[i])*q[i] + bf2f(k1[i])*q[8+i];
    sc[j] = vj ? d * 0.25f : -1e30f;          // dh^-0.5 = 0.25
    mx = fmaxf(mx, sc[j]);
  }
  int anyv = vmask[0] | vmask[1] | vmask[2] | vmask[3] | vmask[4];
  float sum = 0.f;
#pragma unroll
  for (int j = 0; j < 5; ++j) { w[j] = vmask[j] ? __expf(sc[j] - mx) : 0.f; sum += w[j]; }
  float o[16];
#pragma unroll
  for (int i = 0; i < 16; ++i) o[i] = 0.f;
  if (anyv) {
    float inv = 1.f / sum;
#pragma unroll
    for (int j = 0; j < 5; ++j) {
      if (w[j] > 0.f) {
        const u16* vr = Pg + (size_t)mlist[j]*512 + layerOff + 128 + h*16;
        u16x8 v0 = *(const u16x8*)vr;
        u16x8 v1 = *(const u16x8*)(vr + 8);
        float wj = w[j] * inv;
#pragma unroll
        for (int i = 0; i < 8; ++i) { o[i] += wj * bf2f(v0[i]); o[8+i] += wj * bf2f(v1[i]); }
      }
    }
  }
  u16* op = act + nl*136 + h*16;
#pragma unroll
  for (int i = 0; i < 16; ++i) op[i] = f2bf(o[i]);
}

// ---------------- kernel 1: P[n] = [feat@wk1 | feat@wv1 | feat@wk2 | feat@wv2]  (bf16)
__global__ __launch_bounds__(512) void k1_proj(const float* __restrict__ feat,
                                               u16* __restrict__ P,
                                               const u16* __restrict__ wpack, int N) {
  __shared__ __align__(16) u16 s_act[64*136];
  __shared__ __align__(16) u16 s_wt[8192];
  int tid = threadIdx.x;
  int base = blockIdx.x * 64;
  {
    int row = tid >> 3, c0 = (tid & 7) * 16;
    int n = base + row;
    float v[16];
    if (n < N) {
      const float4* fp = (const float4*)(feat + (size_t)n*128 + c0);
#pragma unroll
      for (int q = 0; q < 4; ++q) { float4 f = fp[q]; v[q*4]=f.x; v[q*4+1]=f.y; v[q*4+2]=f.z; v[q*4+3]=f.w; }
    } else {
#pragma unroll
      for (int i = 0; i < 16; ++i) v[i] = 0.f;
    }
#pragma unroll
    for (int i = 0; i < 16; ++i) s_act[row*136 + c0 + i] = f2bf(v[i]);
  }
  __syncthreads();
  int wave = tid >> 6, lane = tid & 63;
  int rt = wave >> 1, cbase = (wave & 1) * 4;
  int l15 = lane & 15, quad = lane >> 4;
  f32x4 z = {0.f,0.f,0.f,0.f};
  for (int wsel = 0; wsel < 4; ++wsel) {
    f32x4 acc[4] = {z,z,z,z};
    run_gemm128<4>(wpack + (size_t)(1 + wsel)*16384, s_act, 136, 0, 128, acc, s_wt, tid, 512, rt, cbase, lane);
    // bounce C through LDS (reuse s_wt) for coalesced 16B global stores
#pragma unroll
    for (int t = 0; t < 4; ++t)
#pragma unroll
      for (int r = 0; r < 4; ++r)
        s_wt[(rt*16 + quad*4 + r)*128 + (cbase + t)*16 + l15] = f2bf(acc[t][r]);
    __syncthreads();
    const uint4* src = (const uint4*)s_wt;
    for (int i = tid; i < 1024; i += 512) {
      int row = i >> 4, c8 = i & 15;
      int n = base + row;
      if (n < N) *(uint4*)(P + (size_t)n*512 + wsel*128 + c8*8) = src[i];
    }
    __syncthreads();
  }
}

// ---------------- kernel 2: fused two transformer blocks + head, 32 nodes/block
struct K2Args {
  const float* feat; const int* nidx; const void* nval; const int* flag;
  const u16* P; const u16* wpack;
  const float* bo1; const float* b1a; const float* b1b;
  const float* g1a; const float* be1a; const float* g1b; const float* be1b;
  const float* bo2; const float* b2a; const float* b2b;
  const float* g2a; const float* be2a; const float* g2b; const float* be2b;
  const float* b4; float* out; int N;
};

__global__ __launch_bounds__(256) void k2_fused(K2Args a) {
  __shared__ __align__(16) u16   s_act[32*136];  // current activation, bf16 (MFMA A)
  __shared__ __align__(16) float s_xf[32*132];   // fp32 residual / post-LN x
  __shared__ __align__(16) u16   s_h1[32*264];   // FFN hidden (256) / q buffer (128)
  __shared__ __align__(16) u16   s_wt[8192];     // staged weight chunk (64K x 128 bf16)
  __shared__ float s_red[32*4];
  __shared__ int   s_nidx[160];
  __shared__ u8    s_nval[160];

  int tid = threadIdx.x;
  int base = blockIdx.x * 32;
  int wave = tid >> 6, lane = tid & 63;
  int rt = wave >> 1, cb4 = (wave & 1) * 4, cb2 = (wave & 1) * 2;
  int l15 = lane & 15, quad = lane >> 4;

  { // load feat rows (fp32 residual + bf16 A-input)
    int row = tid >> 3, c0 = (tid & 7) * 16;
    int n = base + row;
    float v[16];
    if (n < a.N) {
      const float4* fp = (const float4*)(a.feat + (size_t)n*128 + c0);
#pragma unroll
      for (int q = 0; q < 4; ++q) { float4 f = fp[q]; v[q*4]=f.x; v[q*4+1]=f.y; v[q*4+2]=f.z; v[q*4+3]=f.w; }
    } else {
#pragma unroll
      for (int i = 0; i < 16; ++i) v[i] = 0.f;
    }
#pragma unroll
    for (int i = 0; i < 16; ++i) { s_xf[row*132 + c0 + i] = v[i]; s_act[row*136 + c0 + i] = f2bf(v[i]); }
  }
  { // neighbor indices + validity (encoding-agnostic via flag)
    int mode = *a.flag;
    for (int i = tid; i < 160; i += 256) {
      int n2 = base + i/5;
      int idx = 0; u8 val = 0;
      if (n2 < a.N) {
        size_t e = (size_t)base*5 + i;
        idx = a.nidx[e];
        if (mode == 0)      val = (((const int*)a.nval)[e]   != 0);
        else if (mode == 1) val = (((const float*)a.nval)[e] != 0.f);
        else                val = (((const u8*)a.nval)[e]    != 0);
      }
      s_nidx[i] = idx; s_nval[i] = val;
    }
  }
  __syncthreads();

  f32x4 z = {0.f,0.f,0.f,0.f};
  const u16* wp = a.wpack;

  { // P1: q1 = feat @ wq1 -> s_h1
    f32x4 acc[4] = {z,z,z,z};
    run_gemm128<4>(wp + 0, s_act, 136, 0, 128, acc, s_wt, tid, 256, rt, cb4, lane);
    q_epilogue(acc, rt, cb4, lane, s_h1);
    __syncthreads();
  }
  attention(a.P, s_nidx, s_nval, s_h1, s_act, 0, tid);   // P2 -> s_act
  __syncthreads();
  { // P3: @wo1 + bo1 + resid(feat) -> LN(g1a,be1a)
    f32x4 acc[4] = {z,z,z,z};
    run_gemm128<4>(wp + (size_t)5*16384, s_act, 136, 0, 128, acc, s_wt, tid, 256, rt, cb4, lane);
    ln_epilogue(acc, rt, cb4, wave, lane, a.bo1, a.g1a, a.be1a, s_xf, s_act, s_red);
  }
  { // P4: h = relu(x @ w1a + b1a), two column halves -> s_h1[0:256]
    f32x4 acc[4] = {z,z,z,z};
    run_gemm128<4>(wp + (size_t)6*16384, s_act, 136, 0, 128, acc, s_wt, tid, 256, rt, cb4, lane);
    relu_epilogue(acc, rt, cb4, lane, a.b1a, 0, s_h1);
    __syncthreads();
    f32x4 acc2[4] = {z,z,z,z};
    run_gemm128<4>(wp + (size_t)7*16384, s_act, 136, 0, 128, acc2, s_wt, tid, 256, rt, cb4, lane);
    relu_epilogue(acc2, rt, cb4, lane, a.b1a, 128, s_h1);
    __syncthreads();
  }
  { // P5: h @ w1b (K=256) + b1b + resid(x) -> LN(g1b,be1b) => x1
    f32x4 acc[4] = {z,z,z,z};
    run_gemm128<4>(wp + (size_t)8*16384, s_h1, 264, 0,   128, acc, s_wt, tid, 256, rt, cb4, lane);
    run_gemm128<4>(wp + (size_t)9*16384, s_h1, 264, 128, 128, acc, s_wt, tid, 256, rt, cb4, lane);
    ln_epilogue(acc, rt, cb4, wave, lane, a.b1b, a.g1b, a.be1b, s_xf, s_act, s_red);
  }
  { // P6: q2 = x1 @ wq2 -> s_h1
    f32x4 acc[4] = {z,z,z,z};
    run_gemm128<4>(wp + (size_t)10*16384, s_act, 136, 0, 128, acc, s_wt, tid, 256, rt, cb4, lane);
    q_epilogue(acc, rt, cb4, lane, s_h1);
    __syncthreads();
  }
  attention(a.P, s_nidx, s_nval, s_h1, s_act, 256, tid); // P7 (k2/v2 at offsets 256/384)
  __syncthreads();
  { // P8: @wo2 + bo2 + resid(x1) -> LN(g2a,be2a)
    f32x4 acc[4] = {z,z,z,z};
    run_gemm128<4>(wp + (size_t)11*16384, s_act, 136, 0, 128, acc, s_wt, tid, 256, rt, cb4, lane);
    ln_epilogue(acc, rt, cb4, wave, lane, a.bo2, a.g2a, a.be2a, s_xf, s_act, s_red);
  }
  { // P9: relu(x @ w2a + b2a)
    f32x4 acc[4] = {z,z,z,z};
    run_gemm128<4>(wp + (size_t)12*16384, s_act, 136, 0, 128, acc, s_wt, tid, 256, rt, cb4, lane);
    relu_epilogue(acc, rt, cb4, lane, a.b2a, 0, s_h1);
    __syncthreads();
    f32x4 acc2[4] = {z,z,z,z};
    run_gemm128<4>(wp + (size_t)13*16384, s_act, 136, 0, 128, acc2, s_wt, tid, 256, rt, cb4, lane);
    relu_epilogue(acc2, rt, cb4, lane, a.b2a, 128, s_h1);
    __syncthreads();
  }
  { // P10: h @ w2b + b2b + resid -> LN(g2b,be2b) => out2 (bf16 in s_act)
    f32x4 acc[4] = {z,z,z,z};
    run_gemm128<4>(wp + (size_t)14*16384, s_h1, 264, 0,   128, acc, s_wt, tid, 256, rt, cb4, lane);
    run_gemm128<4>(wp + (size_t)15*16384, s_h1, 264, 128, 128, acc, s_wt, tid, 256, rt, cb4, lane);
    ln_epilogue(acc, rt, cb4, wave, lane, a.b2b, a.g2b, a.be2b, s_xf, s_act, s_red);
  }
  { // P11: head: tanh(out2 @ w4 + b4) -> global out (N x 64 fp32)
    f32x4 acc[2] = {z,z};
    const u16* w4 = wp + (size_t)16*16384;
    stageW(w4, s_wt, 4096, tid, 256); __syncthreads();
    mfma_chunk<2>(s_act, 136, 0, s_wt, 64, rt, cb2, acc, lane);
    __syncthreads();
    stageW(w4 + 4096, s_wt, 4096, tid, 256); __syncthreads();
    mfma_chunk<2>(s_act, 136, 64, s_wt, 64, rt, cb2, acc, lane);
#pragma unroll
    for (int t = 0; t < 2; ++t) {
      int col = (cb2 + t)*16 + l15;
      float b = a.b4[col];
#pragma unroll
      for (int r = 0; r < 4; ++r) {
        int row = rt*16 + quad*4 + r;
        int n = base + row;
        if (n < a.N) a.out[(size_t)n*64 + col] = tanhf(acc[t][r] + b);
      }
    }
  }
}

// ---------------- weight pack: fp32 -> bf16 in MFMA-B-fragment-swizzled order
struct PackDesc { const float* src; int srcStride; int row0; int col0; int ncols; int dstOff; };
struct PackArgs { PackDesc d[17]; };

__global__ void pack_kernel(PackArgs pa, u16* __restrict__ wpack) {
  PackDesc d = pa.d[blockIdx.x];
  int total = 128 * d.ncols;
  for (int e = threadIdx.x; e < total; e += blockDim.x) {
    int k, n;
    if (d.ncols == 128) { k = e >> 7; n = e & 127; }
    else                { k = e >> 6; n = e & 63; }
    float v = d.src[(size_t)(d.row0 + k) * d.srcStride + d.col0 + n];
    int kb = k >> 5, q = (k >> 3) & 3, j = k & 7;
    wpack[d.dstOff + ((kb*4 + q) * d.ncols + n) * 8 + j] = f2bf(v);
  }
}

// ---------------- nbr_valid encoding detection (memory-safe for byte/int32/fp32 encodings)
__global__ void detect_kernel(const u32* __restrict__ nv, int* __restrict__ flag) {
  __shared__ int sInt, sFlt;
  if (threadIdx.x == 0) { sInt = 1; sFlt = 1; }
  __syncthreads();
  int okI = 1, okF = 1;
  for (int i = threadIdx.x; i < 2048; i += blockDim.x) {
    u32 w = nv[i];
    if (w > 1u) okI = 0;
    if (w != 0u && w != 0x3F800000u) okF = 0;
  }
  if (!okI) atomicAnd(&sInt, 0);
  if (!okF) atomicAnd(&sFlt, 0);
  __syncthreads();
  if (threadIdx.x == 0) *flag = sInt ? 0 : (sFlt ? 1 : 2);
}

extern "C" void kernel_launch(void* const* d_in, const int* in_sizes, int n_in,
                              void* d_out, int out_size, void* d_ws, size_t ws_size,
                              hipStream_t stream) {
  const float* feat = (const float*)d_in[0];
  const int*   nidx = (const int*)d_in[1];
  const void*  nval = d_in[2];
  int N = in_sizes[0] / 128;

  // workspace: P (N x 512 bf16 = 307 MB) | 17 packed weight chunks | flag
  u16* P     = (u16*)d_ws;
  u16* wpack = P + (size_t)N * 512;
  int* flag  = (int*)(wpack + (size_t)17 * 16384);

  detect_kernel<<<1, 256, 0, stream>>>((const u32*)nval, flag);

  PackArgs pa;
  int c = 0;
  auto W = [&](int i){ return (const float*)d_in[i]; };
  auto add = [&](const float* src, int stride, int r0, int c0, int ncols){
    pa.d[c] = PackDesc{src, stride, r0, c0, ncols, c * 16384}; ++c;
  };
  add(W(3),  128, 0,   0,   128);  // 0:  wq1
  add(W(4),  128, 0,   0,   128);  // 1:  wk1
  add(W(5),  128, 0,   0,   128);  // 2:  wv1
  add(W(17), 128, 0,   0,   128);  // 3:  wk2
  add(W(18), 128, 0,   0,   128);  // 4:  wv2
  add(W(6),  128, 0,   0,   128);  // 5:  wo1
  add(W(8),  256, 0,   0,   128);  // 6:  w1a lo cols
  add(W(8),  256, 0,   128, 128);  // 7:  w1a hi cols
  add(W(10), 128, 0,   0,   128);  // 8:  w1b k 0..127
  add(W(10), 128, 128, 0,   128);  // 9:  w1b k 128..255
  add(W(16), 128, 0,   0,   128);  // 10: wq2
  add(W(19), 128, 0,   0,   128);  // 11: wo2
  add(W(21), 256, 0,   0,   128);  // 12: w2a lo
  add(W(21), 256, 0,   128, 128);  // 13: w2a hi
  add(W(23), 128, 0,   0,   128);  // 14: w2b k0
  add(W(23), 128, 128, 0,   128);  // 15: w2b k1
  add(W(29), 64,  0,   0,   64);   // 16: w4
  pack_kernel<<<17, 256, 0, stream>>>(pa, wpack);

  k1_proj<<<(N + 63) / 64, 512, 0, stream>>>(feat, P, wpack, N);

  K2Args ka;
  ka.feat = feat; ka.nidx = nidx; ka.nval = nval; ka.flag = flag;
  ka.P = P; ka.wpack = wpack;
  ka.bo1 = W(7);  ka.b1a = W(9);  ka.b1b = W(11);
  ka.g1a = W(12); ka.be1a = W(13); ka.g1b = W(14); ka.be1b = W(15);
  ka.bo2 = W(20); ka.b2a = W(22); ka.b2b = W(24);
  ka.g2a = W(25); ka.be2a = W(26); ka.g2b = W(27); ka.be2b = W(28);
  ka.b4 = W(30); ka.out = (float*)d_out; ka.N = N;
  k2_fused<<<(N + 31) / 32, 256, 0, stream>>>(ka);
}

// Round 2
// 1046.202 us; speedup vs baseline: 1.3617x; 1.3617x over previous
//
#include <hip/hip_runtime.h>
#include <cstdint>
#include <cmath>

using u16 = unsigned short;
using u8  = unsigned char;
using u32 = unsigned int;

typedef __attribute__((ext_vector_type(8))) short short8;
typedef __attribute__((ext_vector_type(8))) unsigned short u16x8;
typedef __attribute__((ext_vector_type(4))) float f32x4;

#define DEV static __device__ __forceinline__

DEV u16 f2bf(float f) {               // fp32 -> bf16 RNE
  u32 u = __builtin_bit_cast(u32, f);
  u = u + 0x7fffu + ((u >> 16) & 1u);
  return (u16)(u >> 16);
}
DEV float bf2f(u16 h) { return __builtin_bit_cast(float, ((u32)h) << 16); }

// ---------------- GEMM with DIRECT global->VGPR B-fragment loads (no LDS staging, no barriers).
// Packed B layout: [(kb*4+quad)*ncols + n]*8 + j  (k = kb*32 + quad*8 + j) -> each lane reads
// 16B contiguous; 16 lanes = 256B coalesced segments; weights are L1/L2-resident broadcast.
// A: LDS row-major bf16 (stride u16s). 16x16x32 layouts: A[m=lane&15][k=quad*8+j],
// B[k=quad*8+j][n=lane&15], C row=quad*4+reg, col=lane&15.
template<int NT, int NKB>
DEV void gemm_direct(const u16* __restrict__ wsrc, int ncols,
                     const u16* act, int strideA, int kbase,
                     f32x4* acc, int rt, int cbase, int lane) {
  int l15 = lane & 15, quad = lane >> 4;
  const u16* arow = act + (rt*16 + l15) * strideA + kbase + quad*8;
#pragma unroll
  for (int kb = 0; kb < NKB; ++kb) {
    short8 af = *(const short8*)(arow + kb*32);
    const u16* wrow = wsrc + (size_t)(kb*4 + quad) * ncols * 8;
#pragma unroll
    for (int t = 0; t < NT; ++t) {
      short8 bf = *(const short8*)(wrow + ((cbase + t)*16 + l15) * 8);
      acc[t] = __builtin_amdgcn_mfma_f32_16x16x32_bf16(af, bf, acc[t], 0, 0, 0);
    }
  }
}

// ---------------- epilogues ----------------
// LayerNorm: v = acc + bias + rxf (fp32 residual lives in REGISTERS, same C-layout tile for
// every gemm in the chain). 16-lane butterfly + 2-half LDS combine. Updates rxf (next residual)
// and writes bf16 post-LN x into act (next A-operand). 2 barriers.
DEV void ln_epi(f32x4* acc, float rxf[4][4], int rt, int cbase, int wave, int lane,
                const float* __restrict__ bias, const float* __restrict__ g,
                const float* __restrict__ be, u16* act, float* red) {
  int l15 = lane & 15, quad = lane >> 4;
  int half = wave & 1;
  float v[4][4];
  float s[4] = {0.f,0.f,0.f,0.f}, ss[4] = {0.f,0.f,0.f,0.f};
#pragma unroll
  for (int t = 0; t < 4; ++t) {
    int col = (cbase + t)*16 + l15;
    float b = bias[col];
#pragma unroll
    for (int r = 0; r < 4; ++r) {
      float val = acc[t][r] + b + rxf[t][r];
      v[t][r] = val;
      s[r] += val; ss[r] += val*val;
    }
  }
#pragma unroll
  for (int m = 1; m < 16; m <<= 1) {
#pragma unroll
    for (int r = 0; r < 4; ++r) {
      s[r]  += __shfl_xor(s[r],  m);
      ss[r] += __shfl_xor(ss[r], m);
    }
  }
  if (l15 == 0) {
#pragma unroll
    for (int r = 0; r < 4; ++r) {
      int row = rt*16 + quad*4 + r;
      red[row*4 + half*2 + 0] = s[r];
      red[row*4 + half*2 + 1] = ss[r];
    }
  }
  __syncthreads();   // also guarantees all prior-phase LDS reads are done before act writes
#pragma unroll
  for (int r = 0; r < 4; ++r) {
    int row = rt*16 + quad*4 + r;
    float st  = red[row*4 + 0] + red[row*4 + 2];
    float sst = red[row*4 + 1] + red[row*4 + 3];
    float mean = st * (1.f/128.f);
    float var  = sst * (1.f/128.f) - mean*mean;
    float rs = rsqrtf(var + 1e-5f);
#pragma unroll
    for (int t = 0; t < 4; ++t) {
      int col = (cbase + t)*16 + l15;
      float xn = (v[t][r] - mean) * rs * g[col] + be[col];
      rxf[t][r] = xn;
      act[row*136 + col] = f2bf(xn);
    }
  }
  __syncthreads();
}

DEV void relu_epi(f32x4* acc, int rt, int cbase, int lane,
                  const float* __restrict__ bias, int colbase, u16* h1) {
  int l15 = lane & 15, quad = lane >> 4;
#pragma unroll
  for (int t = 0; t < 4; ++t) {
    int col = (cbase + t)*16 + l15;
    float b = bias[colbase + col];
#pragma unroll
    for (int r = 0; r < 4; ++r) {
      int row = rt*16 + quad*4 + r;
      float val = fmaxf(acc[t][r] + b, 0.f);
      h1[row*264 + colbase + col] = f2bf(val);
    }
  }
}

DEV void q_epi(f32x4* acc, int rt, int cbase, int lane, u16* dst) {
  int l15 = lane & 15, quad = lane >> 4;
#pragma unroll
  for (int t = 0; t < 4; ++t)
#pragma unroll
    for (int r = 0; r < 4; ++r)
      dst[(rt*16 + quad*4 + r)*264 + (cbase + t)*16 + l15] = f2bf(acc[t][r]);
}

// ---------------- attention: thread = (node, head); softmax fully thread-local over K=5
DEV void attention(const u16* __restrict__ Pg, const int* s_nidx, const u8* s_nval,
                   const u16* qbuf, u16* act, int layerOff, int tid) {
  int nl = tid >> 3, h = tid & 7;
  float q[16];
  {
    const u16* qp = qbuf + nl*264 + h*16;
    u16x8 q0 = *(const u16x8*)qp;
    u16x8 q1 = *(const u16x8*)(qp + 8);
#pragma unroll
    for (int i = 0; i < 8; ++i) { q[i] = bf2f(q0[i]); q[8+i] = bf2f(q1[i]); }
  }
  float sc[5], w[5];
  int mlist[5], vmask[5];
  float mx = -1e30f;
#pragma unroll
  for (int j = 0; j < 5; ++j) {
    int mj = s_nidx[nl*5 + j];
    int vj = s_nval[nl*5 + j];
    mlist[j] = mj; vmask[j] = vj;
    const u16* kr = Pg + (size_t)mj*512 + layerOff + h*16;
    u16x8 k0 = *(const u16x8*)kr;
    u16x8 k1 = *(const u16x8*)(kr + 8);
    float d = 0.f;
#pragma unroll
    for (int i = 0; i < 8; ++i) d += bf2f(k0[i])*q[i] + bf2f(k1[i])*q[8+i];
    sc[j] = vj ? d * 0.25f : -1e30f;          // dh^-0.5 = 0.25
    mx = fmaxf(mx, sc[j]);
  }
  int anyv = vmask[0] | vmask[1] | vmask[2] | vmask[3] | vmask[4];
  float sum = 0.f;
#pragma unroll
  for (int j = 0; j < 5; ++j) { w[j] = vmask[j] ? __expf(sc[j] - mx) : 0.f; sum += w[j]; }
  float o[16];
#pragma unroll
  for (int i = 0; i < 16; ++i) o[i] = 0.f;
  if (anyv) {
    float inv = 1.f / sum;
#pragma unroll
    for (int j = 0; j < 5; ++j) {
      if (w[j] > 0.f) {
        const u16* vr = Pg + (size_t)mlist[j]*512 + layerOff + 128 + h*16;
        u16x8 v0 = *(const u16x8*)vr;
        u16x8 v1 = *(const u16x8*)(vr + 8);
        float wj = w[j] * inv;
#pragma unroll
        for (int i = 0; i < 8; ++i) { o[i] += wj * bf2f(v0[i]); o[8+i] += wj * bf2f(v1[i]); }
      }
    }
  }
  u16* op = act + nl*136 + h*16;
#pragma unroll
  for (int i = 0; i < 16; ++i) op[i] = f2bf(o[i]);
}

// ---------------- kernel 1: P[n] = [feat@wk1 | feat@wv1 | feat@wk2 | feat@wv2]  (bf16)
__global__ __launch_bounds__(512) void k1_proj(const float* __restrict__ feat,
                                               u16* __restrict__ P,
                                               const u16* __restrict__ wpack, int N) {
  __shared__ __align__(16) u16 s_act[64*136];
  __shared__ __align__(16) u16 s_c[64*128];   // C bounce for coalesced 16B stores
  int tid = threadIdx.x;
  int base = blockIdx.x * 64;
  {
    int row = tid >> 3, c0 = (tid & 7) * 16;
    int n = base + row;
    float v[16];
    if (n < N) {
      const float4* fp = (const float4*)(feat + (size_t)n*128 + c0);
#pragma unroll
      for (int q = 0; q < 4; ++q) { float4 f = fp[q]; v[q*4]=f.x; v[q*4+1]=f.y; v[q*4+2]=f.z; v[q*4+3]=f.w; }
    } else {
#pragma unroll
      for (int i = 0; i < 16; ++i) v[i] = 0.f;
    }
#pragma unroll
    for (int i = 0; i < 16; ++i) s_act[row*136 + c0 + i] = f2bf(v[i]);
  }
  __syncthreads();
  int wave = tid >> 6, lane = tid & 63;
  int rt = wave >> 1, cbase = (wave & 1) * 4;
  int l15 = lane & 15, quad = lane >> 4;
  f32x4 z = {0.f,0.f,0.f,0.f};
  for (int wsel = 0; wsel < 4; ++wsel) {
    f32x4 acc[4] = {z,z,z,z};
    gemm_direct<4,4>(wpack + (size_t)(1 + wsel)*16384, 128, s_act, 136, 0, acc, rt, cbase, lane);
    __syncthreads();   // previous iteration's s_c reads done
#pragma unroll
    for (int t = 0; t < 4; ++t)
#pragma unroll
      for (int r = 0; r < 4; ++r)
        s_c[(rt*16 + quad*4 + r)*128 + (cbase + t)*16 + l15] = f2bf(acc[t][r]);
    __syncthreads();
    const uint4* src = (const uint4*)s_c;
    for (int i = tid; i < 1024; i += 512) {
      int row = i >> 4, c8 = i & 15;
      int n = base + row;
      if (n < N) *(uint4*)(P + (size_t)n*512 + wsel*128 + c8*8) = src[i];
    }
  }
}

// ---------------- kernel 2: fused two transformer blocks + head, 32 nodes/block
struct K2Args {
  const float* feat; const int* nidx; const void* nval; const int* flag;
  const u16* P; const u16* wpack;
  const float* bo1; const float* b1a; const float* b1b;
  const float* g1a; const float* be1a; const float* g1b; const float* be1b;
  const float* bo2; const float* b2a; const float* b2b;
  const float* g2a; const float* be2a; const float* g2b; const float* be2b;
  const float* b4; float* out; int N;
};

__global__ __launch_bounds__(256) void k2_fused(K2Args a) {
  __shared__ __align__(16) u16   s_act[32*136];  // current activation, bf16 (MFMA A)
  __shared__ __align__(16) u16   s_h1[32*264];   // FFN hidden (256) / q buffer / fp32 feat stage
  __shared__ float s_red[32*4];
  __shared__ int   s_nidx[160];
  __shared__ u8    s_nval[160];

  int tid = threadIdx.x;
  int base = blockIdx.x * 32;
  int wave = tid >> 6, lane = tid & 63;
  int rt = wave >> 1, cb4 = (wave & 1) * 4, cb2 = (wave & 1) * 2;
  int l15 = lane & 15, quad = lane >> 4;

  { // stage feat rows as fp32 into s_h1 (coalesced), then pick up register residual tile
    float* sF = (float*)s_h1;                  // 32*132 floats == 32*264 u16 exactly
    int row = tid >> 3, c0 = (tid & 7) * 16;
    int n = base + row;
    float v[16];
    if (n < a.N) {
      const float4* fp = (const float4*)(a.feat + (size_t)n*128 + c0);
#pragma unroll
      for (int q = 0; q < 4; ++q) { float4 f = fp[q]; v[q*4]=f.x; v[q*4+1]=f.y; v[q*4+2]=f.z; v[q*4+3]=f.w; }
    } else {
#pragma unroll
      for (int i = 0; i < 16; ++i) v[i] = 0.f;
    }
#pragma unroll
    for (int i = 0; i < 16; ++i) sF[row*132 + c0 + i] = v[i];
  }
  { // neighbor indices + validity (encoding-agnostic via flag)
    int mode = *a.flag;
    for (int i = tid; i < 160; i += 256) {
      int n2 = base + i/5;
      int idx = 0; u8 val = 0;
      if (n2 < a.N) {
        size_t e = (size_t)base*5 + i;
        idx = a.nidx[e];
        if (mode == 0)      val = (((const int*)a.nval)[e]   != 0);
        else if (mode == 1) val = (((const float*)a.nval)[e] != 0.f);
        else                val = (((const u8*)a.nval)[e]    != 0);
      }
      s_nidx[i] = idx; s_nval[i] = val;
    }
  }
  __syncthreads();

  float rxf[4][4];   // fp32 residual tile in registers, C-layout ownership
  {
    const float* sF = (const float*)s_h1;
#pragma unroll
    for (int t = 0; t < 4; ++t) {
      int col = (cb4 + t)*16 + l15;
#pragma unroll
      for (int r = 0; r < 4; ++r) {
        int row = rt*16 + quad*4 + r;
        float f = sF[row*132 + col];
        rxf[t][r] = f;
        s_act[row*136 + col] = f2bf(f);
      }
    }
  }
  __syncthreads();

  f32x4 z = {0.f,0.f,0.f,0.f};
  const u16* wp = a.wpack;

  { // P1: q1 = feat @ wq1 -> s_h1
    f32x4 acc[4] = {z,z,z,z};
    gemm_direct<4,4>(wp + 0, 128, s_act, 136, 0, acc, rt, cb4, lane);
    q_epi(acc, rt, cb4, lane, s_h1);
    __syncthreads();
  }
  attention(a.P, s_nidx, s_nval, s_h1, s_act, 0, tid);   // -> s_act
  __syncthreads();
  { // P3: @wo1 + bo1 + resid(feat) -> LN(g1a,be1a)
    f32x4 acc[4] = {z,z,z,z};
    gemm_direct<4,4>(wp + (size_t)5*16384, 128, s_act, 136, 0, acc, rt, cb4, lane);
    ln_epi(acc, rxf, rt, cb4, wave, lane, a.bo1, a.g1a, a.be1a, s_act, s_red);
  }
  { // P4: h = relu(x @ w1a + b1a), both column halves, one barrier
    f32x4 acc[4] = {z,z,z,z};
    gemm_direct<4,4>(wp + (size_t)6*16384, 128, s_act, 136, 0, acc, rt, cb4, lane);
    relu_epi(acc, rt, cb4, lane, a.b1a, 0, s_h1);
    f32x4 acc2[4] = {z,z,z,z};
    gemm_direct<4,4>(wp + (size_t)7*16384, 128, s_act, 136, 0, acc2, rt, cb4, lane);
    relu_epi(acc2, rt, cb4, lane, a.b1a, 128, s_h1);
    __syncthreads();
  }
  { // P5: h @ w1b (K=256) + b1b + resid(x) -> LN(g1b,be1b) => x1
    f32x4 acc[4] = {z,z,z,z};
    gemm_direct<4,4>(wp + (size_t)8*16384, 128, s_h1, 264, 0,   acc, rt, cb4, lane);
    gemm_direct<4,4>(wp + (size_t)9*16384, 128, s_h1, 264, 128, acc, rt, cb4, lane);
    ln_epi(acc, rxf, rt, cb4, wave, lane, a.b1b, a.g1b, a.be1b, s_act, s_red);
  }
  { // P6: q2 = x1 @ wq2 -> s_h1
    f32x4 acc[4] = {z,z,z,z};
    gemm_direct<4,4>(wp + (size_t)10*16384, 128, s_act, 136, 0, acc, rt, cb4, lane);
    q_epi(acc, rt, cb4, lane, s_h1);
    __syncthreads();
  }
  attention(a.P, s_nidx, s_nval, s_h1, s_act, 256, tid); // k2/v2 at offsets 256/384
  __syncthreads();
  { // P8: @wo2 + bo2 + resid(x1) -> LN(g2a,be2a)
    f32x4 acc[4] = {z,z,z,z};
    gemm_direct<4,4>(wp + (size_t)11*16384, 128, s_act, 136, 0, acc, rt, cb4, lane);
    ln_epi(acc, rxf, rt, cb4, wave, lane, a.bo2, a.g2a, a.be2a, s_act, s_red);
  }
  { // P9: relu(x @ w2a + b2a)
    f32x4 acc[4] = {z,z,z,z};
    gemm_direct<4,4>(wp + (size_t)12*16384, 128, s_act, 136, 0, acc, rt, cb4, lane);
    relu_epi(acc, rt, cb4, lane, a.b2a, 0, s_h1);
    f32x4 acc2[4] = {z,z,z,z};
    gemm_direct<4,4>(wp + (size_t)13*16384, 128, s_act, 136, 0, acc2, rt, cb4, lane);
    relu_epi(acc2, rt, cb4, lane, a.b2a, 128, s_h1);
    __syncthreads();
  }
  { // P10: h @ w2b + b2b + resid -> LN(g2b,be2b) => out2 (bf16 in s_act)
    f32x4 acc[4] = {z,z,z,z};
    gemm_direct<4,4>(wp + (size_t)14*16384, 128, s_h1, 264, 0,   acc, rt, cb4, lane);
    gemm_direct<4,4>(wp + (size_t)15*16384, 128, s_h1, 264, 128, acc, rt, cb4, lane);
    ln_epi(acc, rxf, rt, cb4, wave, lane, a.b2b, a.g2b, a.be2b, s_act, s_red);
  }
  { // P11: head: tanh(out2 @ w4 + b4) -> global out (N x 64 fp32)
    f32x4 acc[2] = {z,z};
    gemm_direct<2,4>(wp + (size_t)16*16384, 64, s_act, 136, 0, acc, rt, cb2, lane);
#pragma unroll
    for (int t = 0; t < 2; ++t) {
      int col = (cb2 + t)*16 + l15;
      float b = a.b4[col];
#pragma unroll
      for (int r = 0; r < 4; ++r) {
        int row = rt*16 + quad*4 + r;
        int n = base + row;
        if (n < a.N) a.out[(size_t)n*64 + col] = tanhf(acc[t][r] + b);
      }
    }
  }
}

// ---------------- weight pack: fp32 -> bf16 in MFMA-B-fragment-swizzled order
struct PackDesc { const float* src; int srcStride; int row0; int col0; int ncols; int dstOff; };
struct PackArgs { PackDesc d[17]; };

__global__ void pack_kernel(PackArgs pa, u16* __restrict__ wpack) {
  PackDesc d = pa.d[blockIdx.x];
  int total = 128 * d.ncols;
  for (int e = threadIdx.x; e < total; e += blockDim.x) {
    int k, n;
    if (d.ncols == 128) { k = e >> 7; n = e & 127; }
    else                { k = e >> 6; n = e & 63; }
    float v = d.src[(size_t)(d.row0 + k) * d.srcStride + d.col0 + n];
    int kb = k >> 5, q = (k >> 3) & 3, j = k & 7;
    wpack[d.dstOff + ((kb*4 + q) * d.ncols + n) * 8 + j] = f2bf(v);
  }
}

// ---------------- nbr_valid encoding detection (memory-safe for byte/int32/fp32 encodings)
__global__ void detect_kernel(const u32* __restrict__ nv, int* __restrict__ flag) {
  __shared__ int sInt, sFlt;
  if (threadIdx.x == 0) { sInt = 1; sFlt = 1; }
  __syncthreads();
  int okI = 1, okF = 1;
  for (int i = threadIdx.x; i < 2048; i += blockDim.x) {
    u32 w = nv[i];
    if (w > 1u) okI = 0;
    if (w != 0u && w != 0x3F800000u) okF = 0;
  }
  if (!okI) atomicAnd(&sInt, 0);
  if (!okF) atomicAnd(&sFlt, 0);
  __syncthreads();
  if (threadIdx.x == 0) *flag = sInt ? 0 : (sFlt ? 1 : 2);
}

extern "C" void kernel_launch(void* const* d_in, const int* in_sizes, int n_in,
                              void* d_out, int out_size, void* d_ws, size_t ws_size,
                              hipStream_t stream) {
  const float* feat = (const float*)d_in[0];
  const int*   nidx = (const int*)d_in[1];
  const void*  nval = d_in[2];
  int N = in_sizes[0] / 128;

  // workspace: P (N x 512 bf16 = 307 MB) | 17 packed weight chunks | flag
  u16* P     = (u16*)d_ws;
  u16* wpack = P + (size_t)N * 512;
  int* flag  = (int*)(wpack + (size_t)17 * 16384);

  detect_kernel<<<1, 256, 0, stream>>>((const u32*)nval, flag);

  PackArgs pa;
  int c = 0;
  auto W = [&](int i){ return (const float*)d_in[i]; };
  auto add = [&](const float* src, int stride, int r0, int c0, int ncols){
    pa.d[c] = PackDesc{src, stride, r0, c0, ncols, c * 16384}; ++c;
  };
  add(W(3),  128, 0,   0,   128);  // 0:  wq1
  add(W(4),  128, 0,   0,   128);  // 1:  wk1
  add(W(5),  128, 0,   0,   128);  // 2:  wv1
  add(W(17), 128, 0,   0,   128);  // 3:  wk2
  add(W(18), 128, 0,   0,   128);  // 4:  wv2
  add(W(6),  128, 0,   0,   128);  // 5:  wo1
  add(W(8),  256, 0,   0,   128);  // 6:  w1a lo cols
  add(W(8),  256, 0,   128, 128);  // 7:  w1a hi cols
  add(W(10), 128, 0,   0,   128);  // 8:  w1b k 0..127
  add(W(10), 128, 128, 0,   128);  // 9:  w1b k 128..255
  add(W(16), 128, 0,   0,   128);  // 10: wq2
  add(W(19), 128, 0,   0,   128);  // 11: wo2
  add(W(21), 256, 0,   0,   128);  // 12: w2a lo
  add(W(21), 256, 0,   128, 128);  // 13: w2a hi
  add(W(23), 128, 0,   0,   128);  // 14: w2b k0
  add(W(23), 128, 128, 0,   128);  // 15: w2b k1
  add(W(29), 64,  0,   0,   64);   // 16: w4
  pack_kernel<<<17, 256, 0, stream>>>(pa, wpack);

  k1_proj<<<(N + 63) / 64, 512, 0, stream>>>(feat, P, wpack, N);

  K2Args ka;
  ka.feat = feat; ka.nidx = nidx; ka.nval = nval; ka.flag = flag;
  ka.P = P; ka.wpack = wpack;
  ka.bo1 = W(7);  ka.b1a = W(9);  ka.b1b = W(11);
  ka.g1a = W(12); ka.be1a = W(13); ka.g1b = W(14); ka.be1b = W(15);
  ka.bo2 = W(20); ka.b2a = W(22); ka.b2b = W(24);
  ka.g2a = W(25); ka.be2a = W(26); ka.g2b = W(27); ka.be2b = W(28);
  ka.b4 = W(30); ka.out = (float*)d_out; ka.N = N;
  k2_fused<<<(N + 31) / 32, 256, 0, stream>>>(ka);
}